// Round 1
// baseline (3127.984 us; speedup 1.0000x reference)
//
#include <hip/hip_runtime.h>
#include <hip/hip_fp16.h>

#define NN 50000
#define NE 800000
#define HD 128

typedef __attribute__((ext_vector_type(4))) float vf32x4;
typedef __attribute__((ext_vector_type(8))) __bf16 vbf16x8;
typedef __attribute__((ext_vector_type(4))) unsigned short vushort4;
typedef __attribute__((ext_vector_type(8))) unsigned short vushort8;
typedef _Float16 half2_t __attribute__((ext_vector_type(2)));
typedef _Float16 half4_t __attribute__((ext_vector_type(4)));

// ---- workspace layout (bytes) ----
constexpr size_t OFF_AGG  = 0;                       // 50000*128*2 = 12,800,000 (f16 agg)
constexpr size_t OFF_CNT  = 12800000;                // 200,000 (float counts)
constexpr size_t OFF_DX   = 13000000;                // 600,000
constexpr size_t ZBYTES   = 13600000;                // zero agg+cnt+dx
constexpr size_t OFF_HBF  = 13600000;                // 12,800,000 (h bf16)
constexpr size_t OFF_HR   = 26400000;                // 12,800,000 (Hr = h@We1_top, bf16)
constexpr size_t OFF_HC   = 39200000;                // 12,800,000 (Hc = h@We1_bot, bf16)
constexpr size_t OFF_WE1P = 52000000;                // 65536
constexpr size_t OFF_WE2P = OFF_WE1P + 65536;        // 32768
constexpr size_t OFF_WC1P = OFF_WE2P + 32768;        // 32768
constexpr size_t OFF_WN1P = OFF_WC1P + 32768;        // 65536
constexpr size_t OFF_WN2P = OFF_WN1P + 65536;        // 32768

__device__ __forceinline__ unsigned short f2bf(float f) {
    unsigned int u = __float_as_uint(f);
    u += 0x7fffu + ((u >> 16) & 1u);
    return (unsigned short)(u >> 16);
}

__device__ __forceinline__ float bf2f(unsigned short b) {
    return __uint_as_float((unsigned int)b << 16);
}

__device__ __forceinline__ float silu(float v) {
    return __fdividef(v, 1.0f + __expf(-v));
}

// packed f16 atomic add (2 elems/op) — halves agg atomic op count vs f32
__device__ __forceinline__ void atomic_add_pk_f16(unsigned short* addr, float f0, float f1) {
    half2_t v;
    v[0] = (_Float16)f0;
    v[1] = (_Float16)f1;
#if __has_builtin(__builtin_amdgcn_flat_atomic_fadd_v2f16)
    __builtin_amdgcn_flat_atomic_fadd_v2f16((half2_t*)addr, v);
#elif __has_builtin(__builtin_amdgcn_global_atomic_fadd_v2f16)
    __builtin_amdgcn_global_atomic_fadd_v2f16((half2_t*)addr, v);
#else
    unsafeAtomicAdd((__half2*)addr, *(__half2*)&v);
#endif
}

// ---- convert h (f32) -> h_bf (bf16), row-major [N,128] ----
__global__ __launch_bounds__(256) void h2bf_kernel(const float* __restrict__ h,
                                                   unsigned short* __restrict__ h_bf) {
    int idx = blockIdx.x * 256 + threadIdx.x;
    vf32x4 v = ((const vf32x4*)h)[idx];
    vushort4 o;
    o[0] = f2bf(v[0]); o[1] = f2bf(v[1]); o[2] = f2bf(v[2]); o[3] = f2bf(v[3]);
    ((vushort4*)h_bf)[idx] = o;
}

// ---- pack weight [K x 128] f32 into per-lane B-fragment bf16 layout ----
__device__ __forceinline__ void pack_one(const float* __restrict__ src,
                                         unsigned short* __restrict__ dst,
                                         int local, int KB) {
    int j = local & 7;
    int lane = (local >> 3) & 63;
    int rest = local >> 9;
    int kb = rest % KB;
    int t = rest / KB;
    int srow = kb * 32 + ((lane >> 4) << 3) + j;
    int scol = t * 16 + (lane & 15);
    dst[local] = f2bf(src[srow * 128 + scol]);
}

__global__ __launch_bounds__(256) void pack_w_kernel(
    const float* __restrict__ We1, const float* __restrict__ We2,
    const float* __restrict__ Wc1, const float* __restrict__ Wn1,
    const float* __restrict__ Wn2,
    unsigned short* __restrict__ We1p, unsigned short* __restrict__ We2p,
    unsigned short* __restrict__ Wc1p, unsigned short* __restrict__ Wn1p,
    unsigned short* __restrict__ Wn2p) {
    int idx = blockIdx.x * 256 + threadIdx.x;
    if (idx < 32768)       pack_one(We1, We1p, idx, 8);
    else if (idx < 49152)  pack_one(We2, We2p, idx - 32768, 4);
    else if (idx < 65536)  pack_one(Wc1, Wc1p, idx - 49152, 4);
    else if (idx < 98304)  pack_one(Wn1, Wn1p, idx - 65536, 8);
    else                   pack_one(Wn2, Wn2p, idx - 98304, 4);
}

// ---- precompute Hr = h @ We1[0:128,:], Hc = h @ We1[128:256,:] (bf16 out) ----
// Removes the per-edge K=256 layer-1 GEMM: edge layer1 = Hr[row]+Hc[col]+d2*We1_last+be1.
__global__ __launch_bounds__(256, 4) void hprep_kernel(
    const unsigned short* __restrict__ h_bf,
    const unsigned short* __restrict__ We1p,
    unsigned short* __restrict__ hr, unsigned short* __restrict__ hc) {
    const int tid = threadIdx.x;
    const int nbase = blockIdx.x * 64;
    const int wave = tid >> 6, lane = tid & 63;
    const int li = lane & 15, grp = lane >> 4;

    int mynode = nbase + wave * 16 + li;
    if (mynode >= NN) mynode = NN - 1;

    vbf16x8 af[4];
    const unsigned short* ph = h_bf + (size_t)mynode * 128 + grp * 8;
#pragma unroll
    for (int kb = 0; kb < 4; kb++) af[kb] = *(const vbf16x8*)(ph + kb * 32);

    const vf32x4 vzero = {0.f, 0.f, 0.f, 0.f};
    vf32x4 ar[8], ac[8];
#pragma unroll
    for (int t = 0; t < 8; t++) { ar[t] = vzero; ac[t] = vzero; }
#pragma unroll
    for (int kb = 0; kb < 4; kb++) {
#pragma unroll
        for (int t = 0; t < 8; t++) {
            vbf16x8 br = *(const vbf16x8*)(We1p + ((t * 8 + kb) * 64 + lane) * 8);
            ar[t] = __builtin_amdgcn_mfma_f32_16x16x32_bf16(af[kb], br, ar[t], 0, 0, 0);
            vbf16x8 bc_ = *(const vbf16x8*)(We1p + ((t * 8 + 4 + kb) * 64 + lane) * 8);
            ac[t] = __builtin_amdgcn_mfma_f32_16x16x32_bf16(af[kb], bc_, ac[t], 0, 0, 0);
        }
    }
    // C layout: row = grp*4+r, col = t*16+li
#pragma unroll
    for (int t = 0; t < 8; t++) {
        int col = t * 16 + li;
#pragma unroll
        for (int r = 0; r < 4; r++) {
            int node = nbase + wave * 16 + grp * 4 + r;
            if (node < NN) {
                hr[(size_t)node * 128 + col] = f2bf(ar[t][r]);
                hc[(size_t)node * 128 + col] = f2bf(ac[t][r]);
            }
        }
    }
}

// ---- edge kernel: 64 edges per block, 4 waves x 16 edges ----
// layer1 via precomputed Hr/Hc (register-built A-frags, no LDS round-trip);
// agg scatter via packed f16 atomics (64 ops/edge instead of 128 f32 ops).
__global__ __launch_bounds__(256, 4) void edge_kernel(
    const float* __restrict__ x, const int* __restrict__ ei,
    const unsigned short* __restrict__ hr, const unsigned short* __restrict__ hc,
    const unsigned short* __restrict__ We2p, const unsigned short* __restrict__ Wc1p,
    const float* __restrict__ We1, const float* __restrict__ be1,
    const float* __restrict__ be2, const float* __restrict__ bc1,
    const float* __restrict__ Wc2, const float* __restrict__ bc2,
    float* __restrict__ counts, float* __restrict__ dxsum,
    unsigned short* __restrict__ aggh) {

    __shared__ __align__(16) unsigned short s_ef[64 * 136];
    __shared__ float s_rel[64 * 4];
    __shared__ int s_row[64];
    __shared__ int s_col[64];

    const int tid = threadIdx.x;
    const int ebase = blockIdx.x * 64;

    if (tid < 64) {
        int e = ebase + tid;
        int r = ei[e], c = ei[NE + e];
        s_row[tid] = r;
        s_col[tid] = c;
        float d0 = x[r * 3 + 0] - x[c * 3 + 0];
        float d1 = x[r * 3 + 1] - x[c * 3 + 1];
        float d2v = x[r * 3 + 2] - x[c * 3 + 2];
        s_rel[tid * 4 + 0] = d0;
        s_rel[tid * 4 + 1] = d1;
        s_rel[tid * 4 + 2] = d2v;
        s_rel[tid * 4 + 3] = d0 * d0 + d1 * d1 + d2v * d2v;
    }
    __syncthreads();

    const int wave = tid >> 6, lane = tid & 63;
    const int li = lane & 15, grp = lane >> 4;
    const int el = wave * 16 + li;
    const vf32x4 vzero = {0.f, 0.f, 0.f, 0.f};

    // ---- build ef1 A-fragments in registers: silu(Hr[row]+Hc[col]+d2*We1L+be1) ----
    vbf16x8 af[4];
    {
        const unsigned short* pr = hr + (size_t)s_row[el] * 128 + grp * 8;
        const unsigned short* pc = hc + (size_t)s_col[el] * 128 + grp * 8;
        const float d2e = s_rel[el * 4 + 3];
        const float* wlast = We1 + 256 * 128;
#pragma unroll
        for (int kb = 0; kb < 4; kb++) {
            vushort8 ua = *(const vushort8*)(pr + kb * 32);
            vushort8 ub = *(const vushort8*)(pc + kb * 32);
            int cbase = kb * 32 + grp * 8;
            vushort8 o;
#pragma unroll
            for (int j = 0; j < 8; j++) {
                float v = bf2f(ua[j]) + bf2f(ub[j]) + d2e * wlast[cbase + j] + be1[cbase + j];
                o[j] = f2bf(silu(v));
            }
            af[kb] = *(vbf16x8*)&o;
        }
    }

    // ---- layer 2: ef1 @ We2[128,128] ----
    vf32x4 acc[8];
#pragma unroll
    for (int t = 0; t < 8; t++) acc[t] = vzero;
#pragma unroll
    for (int kb = 0; kb < 4; kb++) {
#pragma unroll
        for (int t = 0; t < 8; t++) {
            vbf16x8 b = *(const vbf16x8*)(We2p + ((t * 4 + kb) * 64 + lane) * 8);
            acc[t] = __builtin_amdgcn_mfma_f32_16x16x32_bf16(af[kb], b, acc[t], 0, 0, 0);
        }
    }
    // epilogue: silu -> s_ef (bf16)
#pragma unroll
    for (int t = 0; t < 8; t++) {
        int col = t * 16 + li;
        float b2 = be2[col];
#pragma unroll
        for (int r = 0; r < 4; r++)
            s_ef[(wave * 16 + grp * 4 + r) * 136 + col] = f2bf(silu(acc[t][r] + b2));
    }
    __syncthreads();

    // ---- gate: silu(ef @ Wc1 + bc1) . Wc2 + bc2 ----
#pragma unroll
    for (int t = 0; t < 8; t++) acc[t] = vzero;
    {
        const unsigned short* arow = s_ef + (wave * 16 + li) * 136 + grp * 8;
#pragma unroll
        for (int kb = 0; kb < 4; kb++) {
            vbf16x8 a = *(const vbf16x8*)(arow + kb * 32);
#pragma unroll
            for (int t = 0; t < 8; t++) {
                vbf16x8 b = *(const vbf16x8*)(Wc1p + ((t * 4 + kb) * 64 + lane) * 8);
                acc[t] = __builtin_amdgcn_mfma_f32_16x16x32_bf16(a, b, acc[t], 0, 0, 0);
            }
        }
    }
    float gp[4] = {0.f, 0.f, 0.f, 0.f};
#pragma unroll
    for (int t = 0; t < 8; t++) {
        int col = t * 16 + li;
        float bc = bc1[col], w2 = Wc2[col];
#pragma unroll
        for (int r = 0; r < 4; r++) gp[r] += silu(acc[t][r] + bc) * w2;
    }
#pragma unroll
    for (int r = 0; r < 4; r++) {
#pragma unroll
        for (int d = 1; d < 16; d <<= 1) gp[r] += __shfl_xor(gp[r], d, 16);
        gp[r] += bc2[0];
    }

    // ---- dx / counts scatter (cheap: 4 atomics per edge) ----
#pragma unroll
    for (int r = 0; r < 4; r++) {
        int e2 = wave * 16 + grp * 4 + r;
        int node = s_row[e2];
        if (li < 3)
            atomicAdd(&dxsum[node * 3 + li], s_rel[e2 * 4 + li] * gp[r]);
        else if (li == 3)
            atomicAdd(&counts[node], 1.0f);
    }

    // ---- agg scatter: 4 threads/edge, 32 cols each, packed f16 atomics ----
    // s_ef is stable (no writes since the pre-gate barrier).
    {
        int e2 = tid >> 2;
        int seg = tid & 3;
        int node = s_row[e2];
        const unsigned short* src = s_ef + e2 * 136 + seg * 32;
        unsigned short* dst = aggh + (size_t)node * 128 + seg * 32;
#pragma unroll
        for (int k = 0; k < 4; k++) {
            vushort8 u = *(const vushort8*)(src + k * 8);
#pragma unroll
            for (int p = 0; p < 4; p++)
                atomic_add_pk_f16(dst + k * 8 + p * 2, bf2f(u[2 * p]), bf2f(u[2 * p + 1]));
        }
    }
}

// ---- node kernel: 64 nodes per block ----
__global__ __launch_bounds__(256, 4) void node_kernel(
    const float* __restrict__ x, const float* __restrict__ h32,
    const unsigned short* __restrict__ h_bf,
    const float* __restrict__ counts, const float* __restrict__ dxsum,
    const unsigned short* __restrict__ aggh,
    const unsigned short* __restrict__ Wn1p, const unsigned short* __restrict__ Wn2p,
    const float* __restrict__ bn1, const float* __restrict__ bn2,
    const float* __restrict__ gamma, const float* __restrict__ beta,
    float* __restrict__ out) {

    __shared__ __align__(16) unsigned short s_agg[64 * 136];
    __shared__ __align__(16) unsigned short s_ef[64 * 136];

    const int tid = threadIdx.x;
    const int nbase = blockIdx.x * 64;

    // x_out = x + dx/cnt
    {
        int idx = blockIdx.x * 192 + tid;
        if (tid < 192 && idx < NN * 3) {
            int node = idx / 3;
            float cnt = fmaxf(counts[node], 1.0f);
            out[idx] = x[idx] + dxsum[idx] / cnt;
        }
    }
    // stage agg (f16 -> bf16, divided by count)
#pragma unroll
    for (int i = 0; i < 8; i++) {
        int flat = i * 256 + tid;
        int row = flat >> 5, q = flat & 31;
        int node = nbase + row;
        if (node >= NN) node = NN - 1;
        float inv = 1.0f / fmaxf(counts[node], 1.0f);
        half4_t v = *(const half4_t*)(aggh + (size_t)node * 128 + q * 4);
        vushort4 o;
        o[0] = f2bf((float)v[0] * inv); o[1] = f2bf((float)v[1] * inv);
        o[2] = f2bf((float)v[2] * inv); o[3] = f2bf((float)v[3] * inv);
        *(vushort4*)(&s_agg[row * 136 + q * 4]) = o;
    }
    __syncthreads();

    const int wave = tid >> 6, lane = tid & 63;
    const int li = lane & 15, grp = lane >> 4;
    const vf32x4 vzero = {0.f, 0.f, 0.f, 0.f};

    int mynode = nbase + wave * 16 + li;
    if (mynode >= NN) mynode = NN - 1;

    // GEMM1: [64,256] @ Wn1[256,128] ; A = [h (direct global) | agg (LDS)]
    vbf16x8 af[8];
    {
        const unsigned short* ph = h_bf + (size_t)mynode * 128 + grp * 8;
#pragma unroll
        for (int kb = 0; kb < 4; kb++) af[kb] = *(const vbf16x8*)(ph + kb * 32);
        const unsigned short* pa = s_agg + (wave * 16 + li) * 136 + grp * 8;
#pragma unroll
        for (int kb = 0; kb < 4; kb++) af[4 + kb] = *(const vbf16x8*)(pa + kb * 32);
    }
    vf32x4 acc[8];
#pragma unroll
    for (int t = 0; t < 8; t++) acc[t] = vzero;
#pragma unroll
    for (int kb = 0; kb < 8; kb++) {
#pragma unroll
        for (int t = 0; t < 8; t++) {
            vbf16x8 b = *(const vbf16x8*)(Wn1p + ((t * 8 + kb) * 64 + lane) * 8);
            acc[t] = __builtin_amdgcn_mfma_f32_16x16x32_bf16(af[kb], b, acc[t], 0, 0, 0);
        }
    }
#pragma unroll
    for (int t = 0; t < 8; t++) {
        int col = t * 16 + li;
        float b1 = bn1[col];
#pragma unroll
        for (int r = 0; r < 4; r++) {
            float v = silu(acc[t][r] + b1);
            s_ef[(wave * 16 + grp * 4 + r) * 136 + col] = f2bf(v);
        }
    }
    __syncthreads();

    // GEMM2: @ Wn2[128,128] + bn2 + h, then LN + silu
#pragma unroll
    for (int t = 0; t < 8; t++) acc[t] = vzero;
    {
        const unsigned short* arow = s_ef + (wave * 16 + li) * 136 + grp * 8;
#pragma unroll
        for (int kb = 0; kb < 4; kb++) {
            vbf16x8 a = *(const vbf16x8*)(arow + kb * 32);
#pragma unroll
            for (int t = 0; t < 8; t++) {
                vbf16x8 b = *(const vbf16x8*)(Wn2p + ((t * 4 + kb) * 64 + lane) * 8);
                acc[t] = __builtin_amdgcn_mfma_f32_16x16x32_bf16(a, b, acc[t], 0, 0, 0);
            }
        }
    }
    float h2v[8][4];
    float sum[4] = {0.f, 0.f, 0.f, 0.f}, sq[4] = {0.f, 0.f, 0.f, 0.f};
#pragma unroll
    for (int t = 0; t < 8; t++) {
        int col = t * 16 + li;
        float b2 = bn2[col];
#pragma unroll
        for (int r = 0; r < 4; r++) {
            int node = nbase + wave * 16 + grp * 4 + r;
            int nc = node < NN ? node : NN - 1;
            float v = acc[t][r] + b2 + h32[(size_t)nc * 128 + col];
            h2v[t][r] = v;
            sum[r] += v;
            sq[r] += v * v;
        }
    }
    float mu[4], rstd[4];
#pragma unroll
    for (int r = 0; r < 4; r++) {
#pragma unroll
        for (int d = 1; d < 16; d <<= 1) {
            sum[r] += __shfl_xor(sum[r], d, 16);
            sq[r] += __shfl_xor(sq[r], d, 16);
        }
        mu[r] = sum[r] * (1.0f / 128.0f);
        float var = sq[r] * (1.0f / 128.0f) - mu[r] * mu[r];
        rstd[r] = rsqrtf(var + 1e-5f);
    }
#pragma unroll
    for (int t = 0; t < 8; t++) {
        int col = t * 16 + li;
        float g = gamma[col], bt = beta[col];
#pragma unroll
        for (int r = 0; r < 4; r++) {
            int node = nbase + wave * 16 + grp * 4 + r;
            if (node < NN) {
                float vn = (h2v[t][r] - mu[r]) * rstd[r] * g + bt;
                out[NN * 3 + (size_t)node * 128 + col] = silu(vn);
            }
        }
    }
}

extern "C" void kernel_launch(void* const* d_in, const int* in_sizes, int n_in,
                              void* d_out, int out_size, void* d_ws, size_t ws_size,
                              hipStream_t stream) {
    const float* x     = (const float*)d_in[0];
    const float* h     = (const float*)d_in[1];
    const int* ei      = (const int*)d_in[2];
    const float* We1   = (const float*)d_in[3];
    const float* be1   = (const float*)d_in[4];
    const float* We2   = (const float*)d_in[5];
    const float* be2   = (const float*)d_in[6];
    const float* Wc1   = (const float*)d_in[7];
    const float* bc1   = (const float*)d_in[8];
    const float* Wc2   = (const float*)d_in[9];
    const float* bc2   = (const float*)d_in[10];
    const float* Wn1   = (const float*)d_in[11];
    const float* bn1   = (const float*)d_in[12];
    const float* Wn2   = (const float*)d_in[13];
    const float* bn2   = (const float*)d_in[14];
    const float* gamma = (const float*)d_in[15];
    const float* beta  = (const float*)d_in[16];
    float* out = (float*)d_out;

    char* ws = (char*)d_ws;
    unsigned short* aggh  = (unsigned short*)(ws + OFF_AGG);
    float* counts         = (float*)(ws + OFF_CNT);
    float* dxsum          = (float*)(ws + OFF_DX);
    unsigned short* h_bf  = (unsigned short*)(ws + OFF_HBF);
    unsigned short* hr_bf = (unsigned short*)(ws + OFF_HR);
    unsigned short* hc_bf = (unsigned short*)(ws + OFF_HC);
    unsigned short* We1p  = (unsigned short*)(ws + OFF_WE1P);
    unsigned short* We2p  = (unsigned short*)(ws + OFF_WE2P);
    unsigned short* Wc1p  = (unsigned short*)(ws + OFF_WC1P);
    unsigned short* Wn1p  = (unsigned short*)(ws + OFF_WN1P);
    unsigned short* Wn2p  = (unsigned short*)(ws + OFF_WN2P);

    hipMemsetAsync(ws, 0, ZBYTES, stream);
    h2bf_kernel<<<NN * 128 / 4 / 256, 256, 0, stream>>>(h, h_bf);
    pack_w_kernel<<<114688 / 256, 256, 0, stream>>>(We1, We2, Wc1, Wn1, Wn2,
                                                    We1p, We2p, Wc1p, Wn1p, Wn2p);
    hprep_kernel<<<(NN + 63) / 64, 256, 0, stream>>>(h_bf, We1p, hr_bf, hc_bf);
    edge_kernel<<<NE / 64, 256, 0, stream>>>(x, ei, hr_bf, hc_bf, We2p, Wc1p,
                                             We1, be1, be2, bc1, Wc2, bc2,
                                             counts, dxsum, aggh);
    node_kernel<<<(NN + 63) / 64, 256, 0, stream>>>(x, h, h_bf, counts, dxsum, aggh,
                                                    Wn1p, Wn2p, bn1, bn2, gamma, beta, out);
}

// Round 3
// 607.557 us; speedup vs baseline: 5.1485x; 5.1485x over previous
//
#include <hip/hip_runtime.h>

#define NN 50000
#define NE 800000
#define HD 128

typedef __attribute__((ext_vector_type(4))) float vf32x4;
typedef __attribute__((ext_vector_type(8))) __bf16 vbf16x8;
typedef __attribute__((ext_vector_type(4))) unsigned short vushort4;
typedef __attribute__((ext_vector_type(8))) unsigned short vushort8;

// ---- workspace layout (bytes) ----
constexpr size_t OFF_AGG   = 0;                        // 50000*128*4 = 25,600,000 (f32 agg)
constexpr size_t OFF_DX    = 25600000;                 // 600,000
constexpr size_t OFF_HIST  = 26200000;                 // 200,000 (int degree)
constexpr size_t OFF_CUR   = 26400000;                 // 200,000 (int cursor)
constexpr size_t ZBYTES    = 26600000;                 // zero agg+dx+hist+cursor
constexpr size_t OFF_START = 26600000;                 // 200,704 (int row_start, padded)
constexpr size_t OFF_PERM  = 26800704;                 // 3,200,000 (int perm)
constexpr size_t OFF_HBF   = 30000704;                 // 12,800,000 (h bf16)
constexpr size_t OFF_HR    = 42800704;                 // 12,800,000 (Hr bf16)
constexpr size_t OFF_HC    = 55600704;                 // 12,800,000 (Hc bf16)
constexpr size_t OFF_WE1P  = 68400704;                 // 65536
constexpr size_t OFF_WE2P  = OFF_WE1P + 65536;         // 32768
constexpr size_t OFF_WC1P  = OFF_WE2P + 32768;         // 32768
constexpr size_t OFF_WN1P  = OFF_WC1P + 32768;         // 65536
constexpr size_t OFF_WN2P  = OFF_WN1P + 65536;         // 32768

__device__ __forceinline__ unsigned short f2bf(float f) {
    unsigned int u = __float_as_uint(f);
    u += 0x7fffu + ((u >> 16) & 1u);
    return (unsigned short)(u >> 16);
}

__device__ __forceinline__ float bf2f(unsigned short b) {
    return __uint_as_float((unsigned int)b << 16);
}

__device__ __forceinline__ float silu(float v) {
    return __fdividef(v, 1.0f + __expf(-v));
}

// ---- convert h (f32) -> h_bf (bf16), row-major [N,128] ----
__global__ __launch_bounds__(256) void h2bf_kernel(const float* __restrict__ h,
                                                   unsigned short* __restrict__ h_bf) {
    int idx = blockIdx.x * 256 + threadIdx.x;
    vf32x4 v = ((const vf32x4*)h)[idx];
    vushort4 o;
    o[0] = f2bf(v[0]); o[1] = f2bf(v[1]); o[2] = f2bf(v[2]); o[3] = f2bf(v[3]);
    ((vushort4*)h_bf)[idx] = o;
}

// ---- pack weight [K x 128] f32 into per-lane B-fragment bf16 layout ----
__device__ __forceinline__ void pack_one(const float* __restrict__ src,
                                         unsigned short* __restrict__ dst,
                                         int local, int KB) {
    int j = local & 7;
    int lane = (local >> 3) & 63;
    int rest = local >> 9;
    int kb = rest % KB;
    int t = rest / KB;
    int srow = kb * 32 + ((lane >> 4) << 3) + j;
    int scol = t * 16 + (lane & 15);
    dst[local] = f2bf(src[srow * 128 + scol]);
}

__global__ __launch_bounds__(256) void pack_w_kernel(
    const float* __restrict__ We1, const float* __restrict__ We2,
    const float* __restrict__ Wc1, const float* __restrict__ Wn1,
    const float* __restrict__ Wn2,
    unsigned short* __restrict__ We1p, unsigned short* __restrict__ We2p,
    unsigned short* __restrict__ Wc1p, unsigned short* __restrict__ Wn1p,
    unsigned short* __restrict__ Wn2p) {
    int idx = blockIdx.x * 256 + threadIdx.x;
    if (idx < 32768)       pack_one(We1, We1p, idx, 8);
    else if (idx < 49152)  pack_one(We2, We2p, idx - 32768, 4);
    else if (idx < 65536)  pack_one(Wc1, Wc1p, idx - 49152, 4);
    else if (idx < 98304)  pack_one(Wn1, Wn1p, idx - 65536, 8);
    else                   pack_one(Wn2, Wn2p, idx - 98304, 4);
}

// ---- CSR build: histogram -> block scan -> scatter ----
__global__ __launch_bounds__(256) void hist_kernel(const int* __restrict__ ei,
                                                   int* __restrict__ hist) {
    int e = blockIdx.x * 256 + threadIdx.x;
    atomicAdd(&hist[ei[e]], 1);
}

#define SCAN_T 1024
#define SCAN_C 49
__global__ __launch_bounds__(1024) void scan_kernel(const int* __restrict__ hist,
                                                    int* __restrict__ row_start) {
    __shared__ int part[SCAN_T];
    int t = threadIdx.x;
    int base = t * SCAN_C;
    int s = 0;
#pragma unroll
    for (int j = 0; j < SCAN_C; j++) {
        int idx = base + j;
        if (idx < NN) s += hist[idx];
    }
    part[t] = s;
    __syncthreads();
    for (int off = 1; off < SCAN_T; off <<= 1) {
        int v = (t >= off) ? part[t - off] : 0;
        __syncthreads();
        part[t] += v;
        __syncthreads();
    }
    int run = (t == 0) ? 0 : part[t - 1];
    for (int j = 0; j < SCAN_C; j++) {
        int idx = base + j;
        if (idx < NN) {
            row_start[idx] = run;
            run += hist[idx];
        }
    }
}

__global__ __launch_bounds__(256) void scatter_kernel(const int* __restrict__ ei,
                                                      const int* __restrict__ row_start,
                                                      int* __restrict__ cursor,
                                                      int* __restrict__ perm) {
    int e = blockIdx.x * 256 + threadIdx.x;
    int r = ei[e];
    int pos = row_start[r] + atomicAdd(&cursor[r], 1);
    perm[pos] = e;
}

// ---- precompute Hr = h @ We1[0:128,:], Hc = h @ We1[128:256,:] (bf16 out) ----
__global__ __launch_bounds__(256, 4) void hprep_kernel(
    const unsigned short* __restrict__ h_bf,
    const unsigned short* __restrict__ We1p,
    unsigned short* __restrict__ hr, unsigned short* __restrict__ hc) {
    const int tid = threadIdx.x;
    const int nbase = blockIdx.x * 64;
    const int wave = tid >> 6, lane = tid & 63;
    const int li = lane & 15, grp = lane >> 4;

    int mynode = nbase + wave * 16 + li;
    if (mynode >= NN) mynode = NN - 1;

    vbf16x8 af[4];
    const unsigned short* ph = h_bf + (size_t)mynode * 128 + grp * 8;
#pragma unroll
    for (int kb = 0; kb < 4; kb++) af[kb] = *(const vbf16x8*)(ph + kb * 32);

    const vf32x4 vzero = {0.f, 0.f, 0.f, 0.f};
    vf32x4 ar[8], ac[8];
#pragma unroll
    for (int t = 0; t < 8; t++) { ar[t] = vzero; ac[t] = vzero; }
#pragma unroll
    for (int kb = 0; kb < 4; kb++) {
#pragma unroll
        for (int t = 0; t < 8; t++) {
            vbf16x8 br = *(const vbf16x8*)(We1p + ((t * 8 + kb) * 64 + lane) * 8);
            ar[t] = __builtin_amdgcn_mfma_f32_16x16x32_bf16(af[kb], br, ar[t], 0, 0, 0);
            vbf16x8 bc_ = *(const vbf16x8*)(We1p + ((t * 8 + 4 + kb) * 64 + lane) * 8);
            ac[t] = __builtin_amdgcn_mfma_f32_16x16x32_bf16(af[kb], bc_, ac[t], 0, 0, 0);
        }
    }
#pragma unroll
    for (int t = 0; t < 8; t++) {
        int col = t * 16 + li;
#pragma unroll
        for (int r = 0; r < 4; r++) {
            int node = nbase + wave * 16 + grp * 4 + r;
            if (node < NN) {
                hr[(size_t)node * 128 + col] = f2bf(ar[t][r]);
                hc[(size_t)node * 128 + col] = f2bf(ac[t][r]);
            }
        }
    }
}

// ---- edge kernel: 64 row-sorted edges per block (via perm), 4 waves x 16 edges ----
// layer1 via precomputed Hr/Hc; agg via segmented in-LDS reduce + sparse f32 atomics.
__global__ __launch_bounds__(256, 4) void edge_kernel(
    const float* __restrict__ x, const int* __restrict__ ei,
    const int* __restrict__ perm,
    const unsigned short* __restrict__ hr, const unsigned short* __restrict__ hc,
    const unsigned short* __restrict__ We2p, const unsigned short* __restrict__ Wc1p,
    const float* __restrict__ We1, const float* __restrict__ be1,
    const float* __restrict__ be2, const float* __restrict__ bc1,
    const float* __restrict__ Wc2, const float* __restrict__ bc2,
    float* __restrict__ dxsum, float* __restrict__ agg) {

    __shared__ __align__(16) unsigned short s_ef[64 * 136];
    __shared__ float s_rel[64 * 4];
    __shared__ int s_row[64];
    __shared__ int s_col[64];

    const int tid = threadIdx.x;
    const int ebase = blockIdx.x * 64;

    if (tid < 64) {
        int e = perm[ebase + tid];
        int r = ei[e], c = ei[NE + e];
        s_row[tid] = r;
        s_col[tid] = c;
        float d0 = x[r * 3 + 0] - x[c * 3 + 0];
        float d1 = x[r * 3 + 1] - x[c * 3 + 1];
        float d2v = x[r * 3 + 2] - x[c * 3 + 2];
        s_rel[tid * 4 + 0] = d0;
        s_rel[tid * 4 + 1] = d1;
        s_rel[tid * 4 + 2] = d2v;
        s_rel[tid * 4 + 3] = d0 * d0 + d1 * d1 + d2v * d2v;
    }
    __syncthreads();

    const int wave = tid >> 6, lane = tid & 63;
    const int li = lane & 15, grp = lane >> 4;
    const int el = wave * 16 + li;
    const vf32x4 vzero = {0.f, 0.f, 0.f, 0.f};

    // ---- build ef1 A-fragments in registers: silu(Hr[row]+Hc[col]+d2*We1L+be1) ----
    vbf16x8 af[4];
    {
        const unsigned short* pr = hr + (size_t)s_row[el] * 128 + grp * 8;
        const unsigned short* pc = hc + (size_t)s_col[el] * 128 + grp * 8;
        const float d2e = s_rel[el * 4 + 3];
        const float* wlast = We1 + 256 * 128;
#pragma unroll
        for (int kb = 0; kb < 4; kb++) {
            vushort8 ua = *(const vushort8*)(pr + kb * 32);
            vushort8 ub = *(const vushort8*)(pc + kb * 32);
            int cbase = kb * 32 + grp * 8;
            vushort8 o;
#pragma unroll
            for (int j = 0; j < 8; j++) {
                float v = bf2f(ua[j]) + bf2f(ub[j]) + d2e * wlast[cbase + j] + be1[cbase + j];
                o[j] = f2bf(silu(v));
            }
            af[kb] = *(vbf16x8*)&o;
        }
    }

    // ---- layer 2: ef1 @ We2[128,128] ----
    vf32x4 acc[8];
#pragma unroll
    for (int t = 0; t < 8; t++) acc[t] = vzero;
#pragma unroll
    for (int kb = 0; kb < 4; kb++) {
#pragma unroll
        for (int t = 0; t < 8; t++) {
            vbf16x8 b = *(const vbf16x8*)(We2p + ((t * 4 + kb) * 64 + lane) * 8);
            acc[t] = __builtin_amdgcn_mfma_f32_16x16x32_bf16(af[kb], b, acc[t], 0, 0, 0);
        }
    }
#pragma unroll
    for (int t = 0; t < 8; t++) {
        int col = t * 16 + li;
        float b2 = be2[col];
#pragma unroll
        for (int r = 0; r < 4; r++)
            s_ef[(wave * 16 + grp * 4 + r) * 136 + col] = f2bf(silu(acc[t][r] + b2));
    }
    __syncthreads();

    // ---- gate: silu(ef @ Wc1 + bc1) . Wc2 + bc2 ----
#pragma unroll
    for (int t = 0; t < 8; t++) acc[t] = vzero;
    {
        const unsigned short* arow = s_ef + (wave * 16 + li) * 136 + grp * 8;
#pragma unroll
        for (int kb = 0; kb < 4; kb++) {
            vbf16x8 a = *(const vbf16x8*)(arow + kb * 32);
#pragma unroll
            for (int t = 0; t < 8; t++) {
                vbf16x8 b = *(const vbf16x8*)(Wc1p + ((t * 4 + kb) * 64 + lane) * 8);
                acc[t] = __builtin_amdgcn_mfma_f32_16x16x32_bf16(a, b, acc[t], 0, 0, 0);
            }
        }
    }
    float gp[4] = {0.f, 0.f, 0.f, 0.f};
#pragma unroll
    for (int t = 0; t < 8; t++) {
        int col = t * 16 + li;
        float bc = bc1[col], w2 = Wc2[col];
#pragma unroll
        for (int r = 0; r < 4; r++) gp[r] += silu(acc[t][r] + bc) * w2;
    }
#pragma unroll
    for (int r = 0; r < 4; r++) {
#pragma unroll
        for (int d = 1; d < 16; d <<= 1) gp[r] += __shfl_xor(gp[r], d, 16);
        gp[r] += bc2[0];
    }

    // ---- dx scatter (3 atomics per edge; counts come from hist) ----
#pragma unroll
    for (int r = 0; r < 4; r++) {
        int e2 = wave * 16 + grp * 4 + r;
        int node = s_row[e2];
        if (li < 3)
            atomicAdd(&dxsum[node * 3 + li], s_rel[e2 * 4 + li] * gp[r]);
    }

    // ---- agg: segmented reduce over row-sorted edges, then sparse f32 atomics ----
    // s_ef final since pre-gate barrier (gate only reads). Rows sorted ascending.
    {
        int col = tid & 127;
        int half = tid >> 7;          // 0 or 1: edges [0,32) / [32,64)
        int ebeg = half * 32;
        float acc2 = 0.f;
        int cur = s_row[ebeg];
#pragma unroll 4
        for (int e = ebeg; e < ebeg + 32; ++e) {
            int rr = s_row[e];
            float v = bf2f(s_ef[e * 136 + col]);
            if (rr != cur) {
                atomicAdd(&agg[(size_t)cur * 128 + col], acc2);
                acc2 = 0.f;
                cur = rr;
            }
            acc2 += v;
        }
        atomicAdd(&agg[(size_t)cur * 128 + col], acc2);
    }
}

// ---- node kernel: 64 nodes per block ----
__global__ __launch_bounds__(256, 4) void node_kernel(
    const float* __restrict__ x, const float* __restrict__ h32,
    const unsigned short* __restrict__ h_bf,
    const int* __restrict__ hist, const float* __restrict__ dxsum,
    const float* __restrict__ agg,
    const unsigned short* __restrict__ Wn1p, const unsigned short* __restrict__ Wn2p,
    const float* __restrict__ bn1, const float* __restrict__ bn2,
    const float* __restrict__ gamma, const float* __restrict__ beta,
    float* __restrict__ out) {

    __shared__ __align__(16) unsigned short s_agg[64 * 136];
    __shared__ __align__(16) unsigned short s_ef[64 * 136];

    const int tid = threadIdx.x;
    const int nbase = blockIdx.x * 64;

    // x_out = x + dx/cnt
    {
        int idx = blockIdx.x * 192 + tid;
        if (tid < 192 && idx < NN * 3) {
            int node = idx / 3;
            float cnt = fmaxf((float)hist[node], 1.0f);
            out[idx] = x[idx] + dxsum[idx] / cnt;
        }
    }
    // stage agg (f32 -> bf16, divided by count)
#pragma unroll
    for (int i = 0; i < 8; i++) {
        int flat = i * 256 + tid;
        int row = flat >> 5, q = flat & 31;
        int node = nbase + row;
        if (node >= NN) node = NN - 1;
        float inv = 1.0f / fmaxf((float)hist[node], 1.0f);
        vf32x4 v = *(const vf32x4*)(agg + (size_t)node * 128 + q * 4);
        vushort4 o;
        o[0] = f2bf(v[0] * inv); o[1] = f2bf(v[1] * inv);
        o[2] = f2bf(v[2] * inv); o[3] = f2bf(v[3] * inv);
        *(vushort4*)(&s_agg[row * 136 + q * 4]) = o;
    }
    __syncthreads();

    const int wave = tid >> 6, lane = tid & 63;
    const int li = lane & 15, grp = lane >> 4;
    const vf32x4 vzero = {0.f, 0.f, 0.f, 0.f};

    int mynode = nbase + wave * 16 + li;
    if (mynode >= NN) mynode = NN - 1;

    // GEMM1: [64,256] @ Wn1[256,128] ; A = [h (direct global) | agg (LDS)]
    vbf16x8 af[8];
    {
        const unsigned short* ph = h_bf + (size_t)mynode * 128 + grp * 8;
#pragma unroll
        for (int kb = 0; kb < 4; kb++) af[kb] = *(const vbf16x8*)(ph + kb * 32);
        const unsigned short* pa = s_agg + (wave * 16 + li) * 136 + grp * 8;
#pragma unroll
        for (int kb = 0; kb < 4; kb++) af[4 + kb] = *(const vbf16x8*)(pa + kb * 32);
    }
    vf32x4 acc[8];
#pragma unroll
    for (int t = 0; t < 8; t++) acc[t] = vzero;
#pragma unroll
    for (int kb = 0; kb < 8; kb++) {
#pragma unroll
        for (int t = 0; t < 8; t++) {
            vbf16x8 b = *(const vbf16x8*)(Wn1p + ((t * 8 + kb) * 64 + lane) * 8);
            acc[t] = __builtin_amdgcn_mfma_f32_16x16x32_bf16(af[kb], b, acc[t], 0, 0, 0);
        }
    }
#pragma unroll
    for (int t = 0; t < 8; t++) {
        int col = t * 16 + li;
        float b1 = bn1[col];
#pragma unroll
        for (int r = 0; r < 4; r++) {
            float v = silu(acc[t][r] + b1);
            s_ef[(wave * 16 + grp * 4 + r) * 136 + col] = f2bf(v);
        }
    }
    __syncthreads();

    // GEMM2: @ Wn2[128,128] + bn2 + h, then LN + silu
#pragma unroll
    for (int t = 0; t < 8; t++) acc[t] = vzero;
    {
        const unsigned short* arow = s_ef + (wave * 16 + li) * 136 + grp * 8;
#pragma unroll
        for (int kb = 0; kb < 4; kb++) {
            vbf16x8 a = *(const vbf16x8*)(arow + kb * 32);
#pragma unroll
            for (int t = 0; t < 8; t++) {
                vbf16x8 b = *(const vbf16x8*)(Wn2p + ((t * 4 + kb) * 64 + lane) * 8);
                acc[t] = __builtin_amdgcn_mfma_f32_16x16x32_bf16(a, b, acc[t], 0, 0, 0);
            }
        }
    }
    float h2v[8][4];
    float sum[4] = {0.f, 0.f, 0.f, 0.f}, sq[4] = {0.f, 0.f, 0.f, 0.f};
#pragma unroll
    for (int t = 0; t < 8; t++) {
        int col = t * 16 + li;
        float b2 = bn2[col];
#pragma unroll
        for (int r = 0; r < 4; r++) {
            int node = nbase + wave * 16 + grp * 4 + r;
            int nc = node < NN ? node : NN - 1;
            float v = acc[t][r] + b2 + h32[(size_t)nc * 128 + col];
            h2v[t][r] = v;
            sum[r] += v;
            sq[r] += v * v;
        }
    }
    float mu[4], rstd[4];
#pragma unroll
    for (int r = 0; r < 4; r++) {
#pragma unroll
        for (int d = 1; d < 16; d <<= 1) {
            sum[r] += __shfl_xor(sum[r], d, 16);
            sq[r] += __shfl_xor(sq[r], d, 16);
        }
        mu[r] = sum[r] * (1.0f / 128.0f);
        float var = sq[r] * (1.0f / 128.0f) - mu[r] * mu[r];
        rstd[r] = rsqrtf(var + 1e-5f);
    }
#pragma unroll
    for (int t = 0; t < 8; t++) {
        int col = t * 16 + li;
        float g = gamma[col], bt = beta[col];
#pragma unroll
        for (int r = 0; r < 4; r++) {
            int node = nbase + wave * 16 + grp * 4 + r;
            if (node < NN) {
                float vn = (h2v[t][r] - mu[r]) * rstd[r] * g + bt;
                out[NN * 3 + (size_t)node * 128 + col] = silu(vn);
            }
        }
    }
}

extern "C" void kernel_launch(void* const* d_in, const int* in_sizes, int n_in,
                              void* d_out, int out_size, void* d_ws, size_t ws_size,
                              hipStream_t stream) {
    const float* x     = (const float*)d_in[0];
    const float* h     = (const float*)d_in[1];
    const int* ei      = (const int*)d_in[2];
    const float* We1   = (const float*)d_in[3];
    const float* be1   = (const float*)d_in[4];
    const float* We2   = (const float*)d_in[5];
    const float* be2   = (const float*)d_in[6];
    const float* Wc1   = (const float*)d_in[7];
    const float* bc1   = (const float*)d_in[8];
    const float* Wc2   = (const float*)d_in[9];
    const float* bc2   = (const float*)d_in[10];
    const float* Wn1   = (const float*)d_in[11];
    const float* bn1   = (const float*)d_in[12];
    const float* Wn2   = (const float*)d_in[13];
    const float* bn2   = (const float*)d_in[14];
    const float* gamma = (const float*)d_in[15];
    const float* beta  = (const float*)d_in[16];
    float* out = (float*)d_out;

    char* ws = (char*)d_ws;
    float* agg            = (float*)(ws + OFF_AGG);
    float* dxsum          = (float*)(ws + OFF_DX);
    int* hist             = (int*)(ws + OFF_HIST);
    int* cursor           = (int*)(ws + OFF_CUR);
    int* row_start        = (int*)(ws + OFF_START);
    int* perm             = (int*)(ws + OFF_PERM);
    unsigned short* h_bf  = (unsigned short*)(ws + OFF_HBF);
    unsigned short* hr_bf = (unsigned short*)(ws + OFF_HR);
    unsigned short* hc_bf = (unsigned short*)(ws + OFF_HC);
    unsigned short* We1p  = (unsigned short*)(ws + OFF_WE1P);
    unsigned short* We2p  = (unsigned short*)(ws + OFF_WE2P);
    unsigned short* Wc1p  = (unsigned short*)(ws + OFF_WC1P);
    unsigned short* Wn1p  = (unsigned short*)(ws + OFF_WN1P);
    unsigned short* Wn2p  = (unsigned short*)(ws + OFF_WN2P);

    hipMemsetAsync(ws, 0, ZBYTES, stream);
    h2bf_kernel<<<NN * 128 / 4 / 256, 256, 0, stream>>>(h, h_bf);
    pack_w_kernel<<<114688 / 256, 256, 0, stream>>>(We1, We2, Wc1, Wn1, Wn2,
                                                    We1p, We2p, Wc1p, Wn1p, Wn2p);
    hist_kernel<<<NE / 256, 256, 0, stream>>>(ei, hist);
    scan_kernel<<<1, SCAN_T, 0, stream>>>(hist, row_start);
    scatter_kernel<<<NE / 256, 256, 0, stream>>>(ei, row_start, cursor, perm);
    hprep_kernel<<<(NN + 63) / 64, 256, 0, stream>>>(h_bf, We1p, hr_bf, hc_bf);
    edge_kernel<<<NE / 64, 256, 0, stream>>>(x, ei, perm, hr_bf, hc_bf, We2p, Wc1p,
                                             We1, be1, be2, bc1, Wc2, bc2,
                                             dxsum, agg);
    node_kernel<<<(NN + 63) / 64, 256, 0, stream>>>(x, h, h_bf, hist, dxsum, agg,
                                                    Wn1p, Wn2p, bn1, bn2, gamma, beta, out);
}

// Round 5
// 496.168 us; speedup vs baseline: 6.3043x; 1.2245x over previous
//
#include <hip/hip_runtime.h>

#define NN 50000
#define NE 800000
#define HD 128

typedef __attribute__((ext_vector_type(4))) float vf32x4;
typedef __attribute__((ext_vector_type(8))) __bf16 vbf16x8;
typedef __attribute__((ext_vector_type(4))) unsigned short vushort4;
typedef __attribute__((ext_vector_type(8))) unsigned short vushort8;

// ---- workspace layout (bytes) ----
constexpr size_t OFF_AGG   = 0;                        // 50000*128*4 = 25,600,000 (f32 agg)
constexpr size_t OFF_DX    = 25600000;                 // 600,000
constexpr size_t OFF_HIST  = 26200000;                 // 200,000 (int degree)
constexpr size_t OFF_CUR   = 26400000;                 // 200,000 (int cursor)
constexpr size_t ZBYTES    = 26600000;                 // zero agg+dx+hist+cursor
constexpr size_t OFF_START = 26600000;                 // 200,704 (int row_start, padded)
constexpr size_t OFF_PERM  = 26800704;                 // 3,200,000 (int perm)
constexpr size_t OFF_HBF   = 30000704;                 // 12,800,000 (h bf16)
constexpr size_t OFF_HR    = 42800704;                 // 12,800,000 (Hr bf16)
constexpr size_t OFF_HC    = 55600704;                 // 12,800,000 (Hc bf16)
constexpr size_t OFF_WE1P  = 68400704;                 // 65536
constexpr size_t OFF_WE2P  = OFF_WE1P + 65536;         // 32768
constexpr size_t OFF_WC1P  = OFF_WE2P + 32768;         // 32768
constexpr size_t OFF_WN1P  = OFF_WC1P + 32768;         // 65536
constexpr size_t OFF_WN2P  = OFF_WN1P + 65536;         // 32768
constexpr size_t OFF_BS    = OFF_WN2P + 32768;         // 1024 (block sums)
constexpr size_t OFF_BO    = OFF_BS + 1024;            // 1024 (block offsets)

#define NB_SCAN 196   // ceil(50000/256)

__device__ __forceinline__ unsigned short f2bf(float f) {
    unsigned int u = __float_as_uint(f);
    u += 0x7fffu + ((u >> 16) & 1u);
    return (unsigned short)(u >> 16);
}

__device__ __forceinline__ float bf2f(unsigned short b) {
    return __uint_as_float((unsigned int)b << 16);
}

__device__ __forceinline__ float silu(float v) {
    return __fdividef(v, 1.0f + __expf(-v));
}

// ---- pack weight [K x 128] f32 into per-lane B-fragment bf16 layout ----
__device__ __forceinline__ void pack_one(const float* __restrict__ src,
                                         unsigned short* __restrict__ dst,
                                         int local, int KB) {
    int j = local & 7;
    int lane = (local >> 3) & 63;
    int rest = local >> 9;
    int kb = rest % KB;
    int t = rest / KB;
    int srow = kb * 32 + ((lane >> 4) << 3) + j;
    int scol = t * 16 + (lane & 15);
    dst[local] = f2bf(src[srow * 128 + scol]);
}

__global__ __launch_bounds__(256) void pack_w_kernel(
    const float* __restrict__ We1, const float* __restrict__ We2,
    const float* __restrict__ Wc1, const float* __restrict__ Wn1,
    const float* __restrict__ Wn2,
    unsigned short* __restrict__ We1p, unsigned short* __restrict__ We2p,
    unsigned short* __restrict__ Wc1p, unsigned short* __restrict__ Wn1p,
    unsigned short* __restrict__ Wn2p) {
    int idx = blockIdx.x * 256 + threadIdx.x;
    if (idx < 32768)       pack_one(We1, We1p, idx, 8);
    else if (idx < 49152)  pack_one(We2, We2p, idx - 32768, 4);
    else if (idx < 65536)  pack_one(Wc1, Wc1p, idx - 49152, 4);
    else if (idx < 98304)  pack_one(Wn1, Wn1p, idx - 65536, 8);
    else                   pack_one(Wn2, Wn2p, idx - 98304, 4);
}

// ---- CSR build: histogram -> 3-pass parallel scan -> scatter ----
__global__ __launch_bounds__(256) void hist_kernel(const int* __restrict__ ei,
                                                   int* __restrict__ hist) {
    int e = blockIdx.x * 256 + threadIdx.x;
    atomicAdd(&hist[ei[e]], 1);
}

__global__ __launch_bounds__(256) void scanA_kernel(const int* __restrict__ hist,
                                                    int* __restrict__ blocksum) {
    __shared__ int sm[256];
    int i = blockIdx.x * 256 + threadIdx.x;
    sm[threadIdx.x] = (i < NN) ? hist[i] : 0;
    __syncthreads();
    for (int off = 128; off > 0; off >>= 1) {
        if (threadIdx.x < off) sm[threadIdx.x] += sm[threadIdx.x + off];
        __syncthreads();
    }
    if (threadIdx.x == 0) blocksum[blockIdx.x] = sm[0];
}

__global__ __launch_bounds__(256) void scanB_kernel(const int* __restrict__ blocksum,
                                                    int* __restrict__ blockoff) {
    __shared__ int sm[256];
    int t = threadIdx.x;
    int v = (t < NB_SCAN) ? blocksum[t] : 0;
    sm[t] = v;
    __syncthreads();
    for (int off = 1; off < 256; off <<= 1) {
        int u = (t >= off) ? sm[t - off] : 0;
        __syncthreads();
        sm[t] += u;
        __syncthreads();
    }
    if (t < NB_SCAN) blockoff[t] = sm[t] - v;   // exclusive
}

__global__ __launch_bounds__(256) void scanC_kernel(const int* __restrict__ hist,
                                                    const int* __restrict__ blockoff,
                                                    int* __restrict__ row_start) {
    __shared__ int sm[256];
    int i = blockIdx.x * 256 + threadIdx.x;
    int t = threadIdx.x;
    int v = (i < NN) ? hist[i] : 0;
    sm[t] = v;
    __syncthreads();
    for (int off = 1; off < 256; off <<= 1) {
        int u = (t >= off) ? sm[t - off] : 0;
        __syncthreads();
        sm[t] += u;
        __syncthreads();
    }
    if (i < NN) row_start[i] = blockoff[blockIdx.x] + sm[t] - v;  // exclusive
}

__global__ __launch_bounds__(256) void scatter_kernel(const int* __restrict__ ei,
                                                      const int* __restrict__ row_start,
                                                      int* __restrict__ cursor,
                                                      int* __restrict__ perm) {
    int e = blockIdx.x * 256 + threadIdx.x;
    int r = ei[e];
    int pos = row_start[r] + atomicAdd(&cursor[r], 1);
    perm[pos] = e;
}

// ---- hprep: h(f32) -> h_bf(bf16) side-output, Hr = h@We1[0:128], Hc = h@We1[128:256] ----
__global__ __launch_bounds__(256, 4) void hprep_kernel(
    const float* __restrict__ h,
    const unsigned short* __restrict__ We1p,
    unsigned short* __restrict__ h_bf,
    unsigned short* __restrict__ hr, unsigned short* __restrict__ hc) {
    const int tid = threadIdx.x;
    const int nbase = blockIdx.x * 64;
    const int wave = tid >> 6, lane = tid & 63;
    const int li = lane & 15, grp = lane >> 4;

    int mynode = nbase + wave * 16 + li;
    if (mynode >= NN) mynode = NN - 1;

    vbf16x8 af[4];
    const float* ph = h + (size_t)mynode * 128 + grp * 8;
    unsigned short* pb = h_bf + (size_t)mynode * 128 + grp * 8;
#pragma unroll
    for (int kb = 0; kb < 4; kb++) {
        vf32x4 lo = *(const vf32x4*)(ph + kb * 32);
        vf32x4 hi = *(const vf32x4*)(ph + kb * 32 + 4);
        vushort8 o;
        o[0] = f2bf(lo[0]); o[1] = f2bf(lo[1]); o[2] = f2bf(lo[2]); o[3] = f2bf(lo[3]);
        o[4] = f2bf(hi[0]); o[5] = f2bf(hi[1]); o[6] = f2bf(hi[2]); o[7] = f2bf(hi[3]);
        *(vushort8*)(pb + kb * 32) = o;           // duplicate writes on clamped rows: same data
        af[kb] = *(vbf16x8*)&o;
    }

    const vf32x4 vzero = {0.f, 0.f, 0.f, 0.f};
    vf32x4 ar[8], ac[8];
#pragma unroll
    for (int t = 0; t < 8; t++) { ar[t] = vzero; ac[t] = vzero; }
#pragma unroll
    for (int kb = 0; kb < 4; kb++) {
#pragma unroll
        for (int t = 0; t < 8; t++) {
            vbf16x8 br = *(const vbf16x8*)(We1p + ((t * 8 + kb) * 64 + lane) * 8);
            ar[t] = __builtin_amdgcn_mfma_f32_16x16x32_bf16(af[kb], br, ar[t], 0, 0, 0);
            vbf16x8 bc_ = *(const vbf16x8*)(We1p + ((t * 8 + 4 + kb) * 64 + lane) * 8);
            ac[t] = __builtin_amdgcn_mfma_f32_16x16x32_bf16(af[kb], bc_, ac[t], 0, 0, 0);
        }
    }
#pragma unroll
    for (int t = 0; t < 8; t++) {
        int col = t * 16 + li;
#pragma unroll
        for (int r = 0; r < 4; r++) {
            int node = nbase + wave * 16 + grp * 4 + r;
            if (node < NN) {
                hr[(size_t)node * 128 + col] = f2bf(ar[t][r]);
                hc[(size_t)node * 128 + col] = f2bf(ac[t][r]);
            }
        }
    }
}

// ---- edge kernel: 64 row-sorted edges per block (via perm), 4 waves x 16 edges ----
// 8 blocks/CU target: LDS 19,968 B * 8 = 159.7 KB, VGPR <= 64.
__global__ __launch_bounds__(256, 8) void edge_kernel(
    const float* __restrict__ x, const int* __restrict__ ei,
    const int* __restrict__ perm,
    const unsigned short* __restrict__ hr, const unsigned short* __restrict__ hc,
    const unsigned short* __restrict__ We2p, const unsigned short* __restrict__ Wc1p,
    const float* __restrict__ We1, const float* __restrict__ be1,
    const float* __restrict__ be2, const float* __restrict__ bc1,
    const float* __restrict__ Wc2, const float* __restrict__ bc2,
    float* __restrict__ dxsum, float* __restrict__ agg) {

    __shared__ __align__(16) unsigned short s_ef[64 * 136];
    __shared__ float s_rel[64 * 4];
    __shared__ float s_wl[128];
    __shared__ float s_b1[128];
    __shared__ int s_row[64];
    __shared__ int s_col[64];

    const int tid = threadIdx.x;
    const int ebase = blockIdx.x * 64;

    if (tid < 64) {
        int e = perm[ebase + tid];
        int r = ei[e], c = ei[NE + e];
        s_row[tid] = r;
        s_col[tid] = c;
        float d0 = x[r * 3 + 0] - x[c * 3 + 0];
        float d1 = x[r * 3 + 1] - x[c * 3 + 1];
        float d2v = x[r * 3 + 2] - x[c * 3 + 2];
        s_rel[tid * 4 + 0] = d0;
        s_rel[tid * 4 + 1] = d1;
        s_rel[tid * 4 + 2] = d2v;
        s_rel[tid * 4 + 3] = d0 * d0 + d1 * d1 + d2v * d2v;
    }
    // stage We1 last row + be1 (the latency-critical A-build constants)
    if (tid < 128) s_wl[tid] = We1[256 * 128 + tid];
    else           s_b1[tid - 128] = be1[tid - 128];
    __syncthreads();

    const int wave = tid >> 6, lane = tid & 63;
    const int li = lane & 15, grp = lane >> 4;
    const int el = wave * 16 + li;
    const vf32x4 vzero = {0.f, 0.f, 0.f, 0.f};

    // ---- build ef1 A-fragments in registers: silu(Hr[row]+Hc[col]+d2*We1L+be1) ----
    vbf16x8 af[4];
    {
        const unsigned short* pr = hr + (size_t)s_row[el] * 128 + grp * 8;
        const unsigned short* pc = hc + (size_t)s_col[el] * 128 + grp * 8;
        const float d2e = s_rel[el * 4 + 3];
#pragma unroll
        for (int kb = 0; kb < 4; kb++) {
            vushort8 ua = *(const vushort8*)(pr + kb * 32);
            vushort8 ub = *(const vushort8*)(pc + kb * 32);
            int cbase = kb * 32 + grp * 8;
            vushort8 o;
#pragma unroll
            for (int j = 0; j < 8; j++) {
                float v = bf2f(ua[j]) + bf2f(ub[j]) + d2e * s_wl[cbase + j] + s_b1[cbase + j];
                o[j] = f2bf(silu(v));
            }
            af[kb] = *(vbf16x8*)&o;
        }
    }

    // ---- layer 2: ef1 @ We2[128,128] ----
    vf32x4 acc[8];
#pragma unroll
    for (int t = 0; t < 8; t++) acc[t] = vzero;
#pragma unroll
    for (int kb = 0; kb < 4; kb++) {
#pragma unroll
        for (int t = 0; t < 8; t++) {
            vbf16x8 b = *(const vbf16x8*)(We2p + ((t * 4 + kb) * 64 + lane) * 8);
            acc[t] = __builtin_amdgcn_mfma_f32_16x16x32_bf16(af[kb], b, acc[t], 0, 0, 0);
        }
    }
#pragma unroll
    for (int t = 0; t < 8; t++) {
        int col = t * 16 + li;
        float b2 = be2[col];
#pragma unroll
        for (int r = 0; r < 4; r++)
            s_ef[(wave * 16 + grp * 4 + r) * 136 + col] = f2bf(silu(acc[t][r] + b2));
    }
    __syncthreads();

    // ---- gate: silu(ef @ Wc1 + bc1) . Wc2 + bc2 ----
#pragma unroll
    for (int t = 0; t < 8; t++) acc[t] = vzero;
    {
        const unsigned short* arow = s_ef + (wave * 16 + li) * 136 + grp * 8;
#pragma unroll
        for (int kb = 0; kb < 4; kb++) {
            vbf16x8 a = *(const vbf16x8*)(arow + kb * 32);
#pragma unroll
            for (int t = 0; t < 8; t++) {
                vbf16x8 b = *(const vbf16x8*)(Wc1p + ((t * 4 + kb) * 64 + lane) * 8);
                acc[t] = __builtin_amdgcn_mfma_f32_16x16x32_bf16(a, b, acc[t], 0, 0, 0);
            }
        }
    }
    float gp[4] = {0.f, 0.f, 0.f, 0.f};
#pragma unroll
    for (int t = 0; t < 8; t++) {
        int col = t * 16 + li;
        float bc = bc1[col], w2 = Wc2[col];
#pragma unroll
        for (int r = 0; r < 4; r++) gp[r] += silu(acc[t][r] + bc) * w2;
    }
#pragma unroll
    for (int r = 0; r < 4; r++) {
#pragma unroll
        for (int d = 1; d < 16; d <<= 1) gp[r] += __shfl_xor(gp[r], d, 16);
        gp[r] += bc2[0];
    }

    // ---- dx scatter (3 atomics per edge; counts come from hist) ----
#pragma unroll
    for (int r = 0; r < 4; r++) {
        int e2 = wave * 16 + grp * 4 + r;
        int node = s_row[e2];
        if (li < 3)
            atomicAdd(&dxsum[node * 3 + li], s_rel[e2 * 4 + li] * gp[r]);
    }

    // ---- agg: segmented reduce (col-pairs, 4 quarter-windows of 16 edges) ----
    // s_ef final since pre-gate barrier (gate only reads). Rows sorted ascending.
    {
        int p = tid & 63;          // col pair: cols 2p, 2p+1
        int q = tid >> 6;          // quarter: edges [q*16, q*16+16)
        int ebeg = q * 16;
        float a0 = 0.f, a1 = 0.f;
        int cur = s_row[ebeg];
#pragma unroll 4
        for (int e = ebeg; e < ebeg + 16; ++e) {
            int rr = s_row[e];
            unsigned int u = *(const unsigned int*)(s_ef + e * 136 + p * 2);
            float v0 = bf2f((unsigned short)(u & 0xffffu));
            float v1 = bf2f((unsigned short)(u >> 16));
            if (rr != cur) {
                atomicAdd(&agg[(size_t)cur * 128 + p * 2], a0);
                atomicAdd(&agg[(size_t)cur * 128 + p * 2 + 1], a1);
                a0 = 0.f; a1 = 0.f;
                cur = rr;
            }
            a0 += v0; a1 += v1;
        }
        atomicAdd(&agg[(size_t)cur * 128 + p * 2], a0);
        atomicAdd(&agg[(size_t)cur * 128 + p * 2 + 1], a1);
    }
}

// ---- node kernel: 64 nodes per block ----
__global__ __launch_bounds__(256, 4) void node_kernel(
    const float* __restrict__ x, const float* __restrict__ h32,
    const unsigned short* __restrict__ h_bf,
    const int* __restrict__ hist, const float* __restrict__ dxsum,
    const float* __restrict__ agg,
    const unsigned short* __restrict__ Wn1p, const unsigned short* __restrict__ Wn2p,
    const float* __restrict__ bn1, const float* __restrict__ bn2,
    const float* __restrict__ gamma, const float* __restrict__ beta,
    float* __restrict__ out) {

    __shared__ __align__(16) unsigned short s_agg[64 * 136];
    __shared__ __align__(16) unsigned short s_ef[64 * 136];

    const int tid = threadIdx.x;
    const int nbase = blockIdx.x * 64;

    // x_out = x + dx/cnt
    {
        int idx = blockIdx.x * 192 + tid;
        if (tid < 192 && idx < NN * 3) {
            int node = idx / 3;
            float cnt = fmaxf((float)hist[node], 1.0f);
            out[idx] = x[idx] + dxsum[idx] / cnt;
        }
    }
    // stage agg (f32 -> bf16, divided by count)
#pragma unroll
    for (int i = 0; i < 8; i++) {
        int flat = i * 256 + tid;
        int row = flat >> 5, q = flat & 31;
        int node = nbase + row;
        if (node >= NN) node = NN - 1;
        float inv = 1.0f / fmaxf((float)hist[node], 1.0f);
        vf32x4 v = *(const vf32x4*)(agg + (size_t)node * 128 + q * 4);
        vushort4 o;
        o[0] = f2bf(v[0] * inv); o[1] = f2bf(v[1] * inv);
        o[2] = f2bf(v[2] * inv); o[3] = f2bf(v[3] * inv);
        *(vushort4*)(&s_agg[row * 136 + q * 4]) = o;
    }
    __syncthreads();

    const int wave = tid >> 6, lane = tid & 63;
    const int li = lane & 15, grp = lane >> 4;
    const vf32x4 vzero = {0.f, 0.f, 0.f, 0.f};

    int mynode = nbase + wave * 16 + li;
    if (mynode >= NN) mynode = NN - 1;

    // GEMM1: [64,256] @ Wn1[256,128] ; A = [h (direct global) | agg (LDS)]
    vbf16x8 af[8];
    {
        const unsigned short* ph = h_bf + (size_t)mynode * 128 + grp * 8;
#pragma unroll
        for (int kb = 0; kb < 4; kb++) af[kb] = *(const vbf16x8*)(ph + kb * 32);
        const unsigned short* pa = s_agg + (wave * 16 + li) * 136 + grp * 8;
#pragma unroll
        for (int kb = 0; kb < 4; kb++) af[4 + kb] = *(const vbf16x8*)(pa + kb * 32);
    }
    vf32x4 acc[8];
#pragma unroll
    for (int t = 0; t < 8; t++) acc[t] = vzero;
#pragma unroll
    for (int kb = 0; kb < 8; kb++) {
#pragma unroll
        for (int t = 0; t < 8; t++) {
            vbf16x8 b = *(const vbf16x8*)(Wn1p + ((t * 8 + kb) * 64 + lane) * 8);
            acc[t] = __builtin_amdgcn_mfma_f32_16x16x32_bf16(af[kb], b, acc[t], 0, 0, 0);
        }
    }
#pragma unroll
    for (int t = 0; t < 8; t++) {
        int col = t * 16 + li;
        float b1 = bn1[col];
#pragma unroll
        for (int r = 0; r < 4; r++) {
            float v = silu(acc[t][r] + b1);
            s_ef[(wave * 16 + grp * 4 + r) * 136 + col] = f2bf(v);
        }
    }
    __syncthreads();

    // GEMM2: @ Wn2[128,128] + bn2 + h, then LN + silu
#pragma unroll
    for (int t = 0; t < 8; t++) acc[t] = vzero;
    {
        const unsigned short* arow = s_ef + (wave * 16 + li) * 136 + grp * 8;
#pragma unroll
        for (int kb = 0; kb < 4; kb++) {
            vbf16x8 a = *(const vbf16x8*)(arow + kb * 32);
#pragma unroll
            for (int t = 0; t < 8; t++) {
                vbf16x8 b = *(const vbf16x8*)(Wn2p + ((t * 4 + kb) * 64 + lane) * 8);
                acc[t] = __builtin_amdgcn_mfma_f32_16x16x32_bf16(a, b, acc[t], 0, 0, 0);
            }
        }
    }
    float h2v[8][4];
    float sum[4] = {0.f, 0.f, 0.f, 0.f}, sq[4] = {0.f, 0.f, 0.f, 0.f};
#pragma unroll
    for (int t = 0; t < 8; t++) {
        int col = t * 16 + li;
        float b2 = bn2[col];
#pragma unroll
        for (int r = 0; r < 4; r++) {
            int node = nbase + wave * 16 + grp * 4 + r;
            int nc = node < NN ? node : NN - 1;
            float v = acc[t][r] + b2 + h32[(size_t)nc * 128 + col];
            h2v[t][r] = v;
            sum[r] += v;
            sq[r] += v * v;
        }
    }
    float mu[4], rstd[4];
#pragma unroll
    for (int r = 0; r < 4; r++) {
#pragma unroll
        for (int d = 1; d < 16; d <<= 1) {
            sum[r] += __shfl_xor(sum[r], d, 16);
            sq[r] += __shfl_xor(sq[r], d, 16);
        }
        mu[r] = sum[r] * (1.0f / 128.0f);
        float var = sq[r] * (1.0f / 128.0f) - mu[r] * mu[r];
        rstd[r] = rsqrtf(var + 1e-5f);
    }
#pragma unroll
    for (int t = 0; t < 8; t++) {
        int col = t * 16 + li;
        float g = gamma[col], bt = beta[col];
#pragma unroll
        for (int r = 0; r < 4; r++) {
            int node = nbase + wave * 16 + grp * 4 + r;
            if (node < NN) {
                float vn = (h2v[t][r] - mu[r]) * rstd[r] * g + bt;
                out[NN * 3 + (size_t)node * 128 + col] = silu(vn);
            }
        }
    }
}

extern "C" void kernel_launch(void* const* d_in, const int* in_sizes, int n_in,
                              void* d_out, int out_size, void* d_ws, size_t ws_size,
                              hipStream_t stream) {
    const float* x     = (const float*)d_in[0];
    const float* h     = (const float*)d_in[1];
    const int* ei      = (const int*)d_in[2];
    const float* We1   = (const float*)d_in[3];
    const float* be1   = (const float*)d_in[4];
    const float* We2   = (const float*)d_in[5];
    const float* be2   = (const float*)d_in[6];
    const float* Wc1   = (const float*)d_in[7];
    const float* bc1   = (const float*)d_in[8];
    const float* Wc2   = (const float*)d_in[9];
    const float* bc2   = (const float*)d_in[10];
    const float* Wn1   = (const float*)d_in[11];
    const float* bn1   = (const float*)d_in[12];
    const float* Wn2   = (const float*)d_in[13];
    const float* bn2   = (const float*)d_in[14];
    const float* gamma = (const float*)d_in[15];
    const float* beta  = (const float*)d_in[16];
    float* out = (float*)d_out;

    char* ws = (char*)d_ws;
    float* agg            = (float*)(ws + OFF_AGG);
    float* dxsum          = (float*)(ws + OFF_DX);
    int* hist             = (int*)(ws + OFF_HIST);
    int* cursor           = (int*)(ws + OFF_CUR);
    int* row_start        = (int*)(ws + OFF_START);
    int* perm             = (int*)(ws + OFF_PERM);
    unsigned short* h_bf  = (unsigned short*)(ws + OFF_HBF);
    unsigned short* hr_bf = (unsigned short*)(ws + OFF_HR);
    unsigned short* hc_bf = (unsigned short*)(ws + OFF_HC);
    unsigned short* We1p  = (unsigned short*)(ws + OFF_WE1P);
    unsigned short* We2p  = (unsigned short*)(ws + OFF_WE2P);
    unsigned short* Wc1p  = (unsigned short*)(ws + OFF_WC1P);
    unsigned short* Wn1p  = (unsigned short*)(ws + OFF_WN1P);
    unsigned short* Wn2p  = (unsigned short*)(ws + OFF_WN2P);
    int* blocksum         = (int*)(ws + OFF_BS);
    int* blockoff         = (int*)(ws + OFF_BO);

    hipMemsetAsync(ws, 0, ZBYTES, stream);
    pack_w_kernel<<<114688 / 256, 256, 0, stream>>>(We1, We2, Wc1, Wn1, Wn2,
                                                    We1p, We2p, Wc1p, Wn1p, Wn2p);
    hist_kernel<<<NE / 256, 256, 0, stream>>>(ei, hist);
    scanA_kernel<<<NB_SCAN, 256, 0, stream>>>(hist, blocksum);
    scanB_kernel<<<1, 256, 0, stream>>>(blocksum, blockoff);
    scanC_kernel<<<NB_SCAN, 256, 0, stream>>>(hist, blockoff, row_start);
    scatter_kernel<<<NE / 256, 256, 0, stream>>>(ei, row_start, cursor, perm);
    hprep_kernel<<<(NN + 63) / 64, 256, 0, stream>>>(h, We1p, h_bf, hr_bf, hc_bf);
    edge_kernel<<<NE / 64, 256, 0, stream>>>(x, ei, perm, hr_bf, hc_bf, We2p, Wc1p,
                                             We1, be1, be2, bc1, Wc2, bc2,
                                             dxsum, agg);
    node_kernel<<<(NN + 63) / 64, 256, 0, stream>>>(x, h, h_bf, hist, dxsum, agg,
                                                    Wn1p, Wn2p, bn1, bn2, gamma, beta, out);
}